// Round 1
// 834.133 us; speedup vs baseline: 1.0114x; 1.0114x over previous
//
#include <hip/hip_runtime.h>

// VDPDropout: B=32, H=2048, DROP_PROP=0.2
//   mu_out[b,h]      = keep[b,h] ? mu_in[b,h] * 1.25f : 0
//   nz[b,h]          = keep[b,h] && (mu_in[b,h] != 0)
//   Sigma_out[b,i,j] = (nz[b,i] && nz[b,j]) ? 1.5625f * Sigma_in[b,i,j] : 0
//
// float32(1.0/0.8)   == 1.25f   exactly
// float32((1/0.8)^2) == 1.5625f exactly
//
// Key structural fact: a 256-thread block covers gid range [blk*256, blk*256+256)
// of float4s; a Sigma row is 512 float4s, so every block lies entirely within ONE
// row (r = gid>>9 is block-uniform). => the row-dropped early-out below is
// wave-uniform: ~20% of blocks skip the Sigma_in load entirely (saves ~107 MB
// of HBM fetch per call; writes are irreducible due to output poisoning).

#define SCALE  1.25f
#define SCALE2 1.5625f

#define B_DIM 32
#define H_DIM 2048

// mu: 65536 floats = 16384 float4s; one float4 per thread.
__global__ void mu_kernel4(const float4* __restrict__ mu4,
                           const int4* __restrict__ keep4,
                           float4* __restrict__ out4) {
    int i = blockIdx.x * blockDim.x + threadIdx.x;
    int4   k = keep4[i];
    float4 m = mu4[i];
    float4 o;
    o.x = k.x ? m.x * SCALE : 0.0f;
    o.y = k.y ? m.y * SCALE : 0.0f;
    o.z = k.z ? m.z * SCALE : 0.0f;
    o.w = k.w ? m.w * SCALE : 0.0f;
    out4[i] = o;
}

// One float4 of Sigma per thread. gid indexes float4s of the flat [B*H*H] array.
__global__ void sigma_kernel(const float* __restrict__ mu_in,
                             const int* __restrict__ keep,
                             const float* __restrict__ Sigma_in,
                             float* __restrict__ Sigma_out) {
    const int H4 = H_DIM / 4;  // 512 float4s per row
    long long gid = (long long)blockIdx.x * blockDim.x + threadIdx.x;

    int r  = (int)(gid >> 9);        // flat row index in [0, B*H) — block-uniform
    int c4 = (int)(gid & (H4 - 1));  // column float4 index
    int b  = r >> 11;                // batch

    float4* __restrict__ Sout4 = (float4*)Sigma_out;

    // Row factor nz[b,i] — uniform across the whole block (see header comment).
    // Dropped row => whole row of output is zero; skip ALL reads of Sigma_in.
    bool nzi = (keep[r] != 0) && (mu_in[r] != 0.0f);
    if (!nzi) {
        float4 z; z.x = 0.0f; z.y = 0.0f; z.z = 0.0f; z.w = 0.0f;
        Sout4[gid] = z;
        return;
    }

    // Column factors: nz[b, 4*c4 .. 4*c4+3] (tiny arrays, L2-resident)
    int col_base4 = b * H4 + c4;
    const int4*   keep4 = (const int4*)keep;
    const float4* mu4   = (const float4*)mu_in;
    int4   kj = keep4[col_base4];
    float4 mj = mu4[col_base4];

    const float4* __restrict__ Sin4 = (const float4*)Sigma_in;
    float4 s = Sin4[gid];

    float4 o;
    o.x = (kj.x != 0 && mj.x != 0.0f) ? SCALE2 * s.x : 0.0f;
    o.y = (kj.y != 0 && mj.y != 0.0f) ? SCALE2 * s.y : 0.0f;
    o.z = (kj.z != 0 && mj.z != 0.0f) ? SCALE2 * s.z : 0.0f;
    o.w = (kj.w != 0 && mj.w != 0.0f) ? SCALE2 * s.w : 0.0f;
    Sout4[gid] = o;
}

extern "C" void kernel_launch(void* const* d_in, const int* in_sizes, int n_in,
                              void* d_out, int out_size, void* d_ws, size_t ws_size,
                              hipStream_t stream) {
    const float* mu_in    = (const float*)d_in[0];
    const float* Sigma_in = (const float*)d_in[1];
    const int*   keep     = (const int*)d_in[2];

    float* mu_out    = (float*)d_out;
    float* Sigma_out = (float*)d_out + (B_DIM * H_DIM);  // 65536-float offset, 16B-aligned

    // mu_out: 16384 float4s
    {
        int threads = 256;
        int blocks = (B_DIM * H_DIM / 4) / threads;  // 64
        mu_kernel4<<<blocks, threads, 0, stream>>>(
            (const float4*)mu_in, (const int4*)keep, (float4*)mu_out);
    }

    // Sigma_out: 134,217,728 elements = 33,554,432 float4s, 256 thr/block
    {
        long long total4 = (long long)B_DIM * H_DIM * (H_DIM / 4);
        int threads = 256;
        long long blocks = total4 / threads;  // 131072, exact
        sigma_kernel<<<(int)blocks, threads, 0, stream>>>(mu_in, keep, Sigma_in, Sigma_out);
    }
}